// Round 1
// baseline (116.744 us; speedup 1.0000x reference)
//
#include <hip/hip_runtime.h>
#include <hip/hip_bf16.h>

#define N_EDGES   625000
#define HF        128
#define K2        256          // 2*HF
#define MTILE     64           // edges per tile
#define NTILES    ((N_EDGES + MTILE - 1) / MTILE)
#define NBLOCKS   2048

typedef __attribute__((ext_vector_type(8))) short s16x8;
typedef __attribute__((ext_vector_type(4))) float f32x4;

__device__ __forceinline__ short f2bf(float x) {
    unsigned u = __builtin_bit_cast(unsigned, x);
    u += 0x7FFFu + ((u >> 16) & 1u);          // round-to-nearest-even
    return (short)(u >> 16);
}

__global__ __launch_bounds__(256, 3) void mlp_edge_score(
    const float* __restrict__ h,
    const int*   __restrict__ src,
    const int*   __restrict__ dst,
    const float* __restrict__ W1,
    const float* __restrict__ b1,
    const float* __restrict__ W2,
    const float* __restrict__ b2,
    float* __restrict__ out)
{
    __shared__ short lds_a[MTILE * K2];   // 32 KiB He tile, XOR-swizzled rows
    __shared__ float lds_p[4][MTILE];     // per-wave partial scores

    const int t  = threadIdx.x;
    const int w  = t >> 6;      // wave 0..3 (owns hid cols w*32..w*32+31)
    const int l  = t & 63;
    const int lg = l >> 4;      // lane group 0..3
    const int lr = l & 15;      // lane-in-group

    // ---- W1 -> bf16 B-fragments in registers, once per block ----
    // B frag for 16x16x32: col = lr, k = kt*32 + lg*8 + i  (same (g,i)->k map as A)
    s16x8 bfrag[8][2];
    #pragma unroll
    for (int kt = 0; kt < 8; ++kt) {
      #pragma unroll
      for (int nt = 0; nt < 2; ++nt) {
        const int n  = w * 32 + nt * 16 + lr;
        const int kb = kt * 32 + lg * 8;
        s16x8 f;
        #pragma unroll
        for (int i = 0; i < 8; ++i) f[i] = f2bf(W1[(kb + i) * HF + n]);
        bfrag[kt][nt] = f;
      }
    }
    float b1v[2], w2v[2];
    #pragma unroll
    for (int nt = 0; nt < 2; ++nt) {
      const int n = w * 32 + nt * 16 + lr;
      b1v[nt] = b1[n];
      w2v[nt] = W2[n];
    }
    const float b2v = b2[0];

    char* const abase = (char*)lds_a;

    for (int tile = blockIdx.x; tile < NTILES; tile += gridDim.x) {
      const int base = tile * MTILE;

      // ---- stage He tile: row r = [h[src[e]] | h[dst[e]]] as bf16 ----
      // wave w loads 64-float segment (w>>1 : src/dst, w&1 : lo/hi half), lane = row
      {
        const int r = l;
        int e = base + r; if (e >= N_EDGES) e = N_EDGES - 1;
        const int node = (w & 2) ? dst[e] : src[e];
        const float* hp = h + (size_t)node * HF + (w & 1) * 64;
        const int bohi = (w >> 1) * 256 + (w & 1) * 128;   // byte offset within 512B row
        const int sw   = (r & 7) << 4;                     // XOR swizzle (bits 4..6)
        char* rowp = abase + r * 512 + bohi;
        #pragma unroll
        for (int j = 0; j < 8; ++j) {
          f32x4 v0 = *reinterpret_cast<const f32x4*>(hp + j * 8);
          f32x4 v1 = *reinterpret_cast<const f32x4*>(hp + j * 8 + 4);
          s16x8 p;
          p[0]=f2bf(v0[0]); p[1]=f2bf(v0[1]); p[2]=f2bf(v0[2]); p[3]=f2bf(v0[3]);
          p[4]=f2bf(v1[0]); p[5]=f2bf(v1[1]); p[6]=f2bf(v1[2]); p[7]=f2bf(v1[3]);
          *reinterpret_cast<s16x8*>(rowp + ((j * 16) ^ sw)) = p;
        }
      }
      __syncthreads();

      // ---- [64 x 256] @ [256 x 32] per wave, 16x16x32 bf16 MFMA ----
      f32x4 acc[4][2];
      #pragma unroll
      for (int mt = 0; mt < 4; ++mt) {
        acc[mt][0] = (f32x4){0.f, 0.f, 0.f, 0.f};
        acc[mt][1] = (f32x4){0.f, 0.f, 0.f, 0.f};
      }
      #pragma unroll
      for (int kt = 0; kt < 8; ++kt) {
        s16x8 afr[4];
        #pragma unroll
        for (int mt = 0; mt < 4; ++mt) {
          const int row = mt * 16 + lr;
          const int bo  = (kt * 64 + lg * 16) ^ ((row & 7) << 4);
          afr[mt] = *reinterpret_cast<const s16x8*>(abase + row * 512 + bo);
        }
        #pragma unroll
        for (int mt = 0; mt < 4; ++mt) {
          acc[mt][0] = __builtin_amdgcn_mfma_f32_16x16x32_bf16(afr[mt], bfrag[kt][0], acc[mt][0], 0, 0, 0);
          acc[mt][1] = __builtin_amdgcn_mfma_f32_16x16x32_bf16(afr[mt], bfrag[kt][1], acc[mt][1], 0, 0, 0);
        }
      }

      // ---- layer 2 in fp32: relu(acc + b1) . W2, reduce over 128 cols ----
      // C/D layout: col = lr, row-in-tile = lg*4 + rr  (verified m89/m91)
      float s[4][4];
      #pragma unroll
      for (int mt = 0; mt < 4; ++mt)
        #pragma unroll
        for (int rr = 0; rr < 4; ++rr) {
          float v0 = acc[mt][0][rr] + b1v[0]; v0 = v0 > 0.f ? v0 : 0.f;
          float v1 = acc[mt][1][rr] + b1v[1]; v1 = v1 > 0.f ? v1 : 0.f;
          s[mt][rr] = v0 * w2v[0] + v1 * w2v[1];
        }
      #pragma unroll
      for (int mask = 1; mask <= 8; mask <<= 1)
        #pragma unroll
        for (int mt = 0; mt < 4; ++mt)
          #pragma unroll
          for (int rr = 0; rr < 4; ++rr)
            s[mt][rr] += __shfl_xor(s[mt][rr], mask, 64);

      if (lr == 0) {
        #pragma unroll
        for (int mt = 0; mt < 4; ++mt)
          #pragma unroll
          for (int rr = 0; rr < 4; ++rr)
            lds_p[w][mt * 16 + lg * 4 + rr] = s[mt][rr];
      }
      __syncthreads();

      if (t < MTILE) {
        const int e = base + t;
        if (e < N_EDGES)
          out[e] = lds_p[0][t] + lds_p[1][t] + lds_p[2][t] + lds_p[3][t] + b2v;
      }
      // next iteration's staging (after this point) only touches lds_a, whose
      // reads completed before the barrier above; lds_p rewrites happen only
      // after the next barrier.
    }
}

extern "C" void kernel_launch(void* const* d_in, const int* in_sizes, int n_in,
                              void* d_out, int out_size, void* d_ws, size_t ws_size,
                              hipStream_t stream) {
    const float* h   = (const float*)d_in[0];
    const int*   src = (const int*)  d_in[1];
    const int*   dst = (const int*)  d_in[2];
    const float* W1  = (const float*)d_in[3];
    const float* b1  = (const float*)d_in[4];
    const float* W2  = (const float*)d_in[5];
    const float* b2  = (const float*)d_in[6];
    float* out = (float*)d_out;
    mlp_edge_score<<<NBLOCKS, 256, 0, stream>>>(h, src, dst, W1, b1, W2, b2, out);
}

// Round 2
// 89.697 us; speedup vs baseline: 1.3015x; 1.3015x over previous
//
#include <hip/hip_runtime.h>
#include <hip/hip_bf16.h>

#define N_NODES   50000
#define N_EDGES   625000
#define HF        128
#define K2        256          // 2*HF
#define MTILE     64           // edges per tile
#define NTILES    ((N_EDGES + MTILE - 1) / MTILE)
#define MAIN_BLOCKS 256
#define HB_BYTES  ((size_t)N_NODES * HF * sizeof(short))

typedef __attribute__((ext_vector_type(8))) short s16x8;
typedef __attribute__((ext_vector_type(4))) float f32x4;

__device__ __forceinline__ short f2bf(float x) {
    unsigned u = __builtin_bit_cast(unsigned, x);
    u += 0x7FFFu + ((u >> 16) & 1u);          // round-to-nearest-even
    return (short)(u >> 16);
}

// ---------------------------------------------------------------------------
// h (fp32) -> h_bf16 in workspace, one element block = 8 floats per thread
// ---------------------------------------------------------------------------
__global__ void conv_h_kernel(const float* __restrict__ h, short* __restrict__ hb) {
    int i = blockIdx.x * blockDim.x + threadIdx.x;
    const int n8 = N_NODES * HF / 8;           // 800000
    if (i < n8) {
        f32x4 a = ((const f32x4*)h)[i * 2];
        f32x4 b = ((const f32x4*)h)[i * 2 + 1];
        s16x8 p;
        p[0]=f2bf(a[0]); p[1]=f2bf(a[1]); p[2]=f2bf(a[2]); p[3]=f2bf(a[3]);
        p[4]=f2bf(b[0]); p[5]=f2bf(b[1]); p[6]=f2bf(b[2]); p[7]=f2bf(b[3]);
        ((s16x8*)hb)[i] = p;
    }
}

// ---------------------------------------------------------------------------
// Main kernel v2: no LDS staging. 8 waves = 4 row-groups x 2 col-halves.
// Wave (r,c): edges tile*64 + r*16 .. +15, hidden cols c*64 .. +63.
// A-fragments gathered straight from h_bf16 (per-lane 16B loads).
// ---------------------------------------------------------------------------
__device__ __forceinline__ void gatherA(const short* __restrict__ hb,
                                        int sid, int did, int lg, s16x8 (&A)[8]) {
    const s16x8* bs = (const s16x8*)(hb + (size_t)sid * HF);
    const s16x8* bd = (const s16x8*)(hb + (size_t)did * HF);
    // k = kt*32 + lg*8 ; src half kt 0..3, dst half kt 4..7
    A[0] = bs[lg];      A[1] = bs[4 + lg];  A[2] = bs[8 + lg];  A[3] = bs[12 + lg];
    A[4] = bd[lg];      A[5] = bd[4 + lg];  A[6] = bd[8 + lg];  A[7] = bd[12 + lg];
}

__device__ __forceinline__ void step_tile(
    int tile, int g,
    const short* __restrict__ hb,
    const int* __restrict__ src, const int* __restrict__ dst,
    s16x8 (&Acur)[8], s16x8 (&Anext)[8],
    int sidg, int didg,            // ids for tile+g : gather now
    int& sid2, int& did2,          // out: ids for tile+2g
    const s16x8 (&bfrag)[8][4],
    const float (&b1v)[4], const float (&w2v)[4], float b2v,
    float* __restrict__ out,
    float (&lds_p)[2][2][MTILE], int pp,
    int t, int r, int c, int lg, int lr, int myrow)
{
    // ---- issue prefetch gathers for tile+g (stay in flight across barrier) ----
    gatherA(hb, sidg, didg, lg, Anext);

    // ---- prefetch edge ids for tile+2g ----
    {
        int e = (tile + 2 * g) * MTILE + myrow;
        e = e < N_EDGES ? e : N_EDGES - 1;
        sid2 = src[e];
        did2 = dst[e];
    }

    // ---- compute tile: [16 x 256] @ [256 x 64] via 8kt x 4nt MFMA ----
    f32x4 acc[4];
    #pragma unroll
    for (int nt = 0; nt < 4; ++nt) acc[nt] = (f32x4){0.f, 0.f, 0.f, 0.f};
    #pragma unroll
    for (int kt = 0; kt < 8; ++kt) {
        #pragma unroll
        for (int nt = 0; nt < 4; ++nt)
            acc[nt] = __builtin_amdgcn_mfma_f32_16x16x32_bf16(Acur[kt], bfrag[kt][nt], acc[nt], 0, 0, 0);
    }

    // ---- layer 2 in fp32: relu(acc + b1) . W2, partial over this wave's 64 cols ----
    // C/D layout: col = lr (n = nt*16+lr), row-in-16 = lg*4 + rr
    float s0[4];
    #pragma unroll
    for (int rr = 0; rr < 4; ++rr) {
        float a = 0.f;
        #pragma unroll
        for (int nt = 0; nt < 4; ++nt) {
            float v = acc[nt][rr] + b1v[nt];
            v = v > 0.f ? v : 0.f;
            a += v * w2v[nt];
        }
        s0[rr] = a;
    }
    // reduce over the 16 lr lanes (masks 1..8 stay within an lg group)
    #pragma unroll
    for (int mask = 1; mask <= 8; mask <<= 1)
        #pragma unroll
        for (int rr = 0; rr < 4; ++rr)
            s0[rr] += __shfl_xor(s0[rr], mask, 64);

    if (lr == 0) {
        #pragma unroll
        for (int rr = 0; rr < 4; ++rr)
            lds_p[pp][c][r * 16 + lg * 4 + rr] = s0[rr];
    }
    asm volatile("s_waitcnt lgkmcnt(0)" ::: "memory");
    __builtin_amdgcn_s_barrier();          // raw: no vmcnt drain, prefetch survives
    asm volatile("" ::: "memory");

    if (t < MTILE) {
        int e = tile * MTILE + t;
        if (e < N_EDGES)
            out[e] = lds_p[pp][0][t] + lds_p[pp][1][t] + b2v;
    }
}

__global__ __launch_bounds__(512, 2) void mlp_edge_score_v2(
    const short* __restrict__ hb,
    const int*   __restrict__ src,
    const int*   __restrict__ dst,
    const float* __restrict__ W1,
    const float* __restrict__ b1,
    const float* __restrict__ W2,
    const float* __restrict__ b2,
    float* __restrict__ out)
{
    __shared__ float lds_p[2][2][MTILE];   // [phase][c][row] partial scores, 1 KiB

    const int t  = threadIdx.x;
    const int w  = t >> 6;
    const int l  = t & 63;
    const int r  = w >> 1;       // 0..3 row-group
    const int c  = w & 1;        // 0..1 col-half
    const int lg = l >> 4;
    const int lr = l & 15;
    const int myrow = r * 16 + lr;

    // ---- W1 -> bf16 B-fragments in registers, once per block (128 VGPR) ----
    s16x8 bfrag[8][4];
    #pragma unroll
    for (int kt = 0; kt < 8; ++kt)
        #pragma unroll
        for (int nt = 0; nt < 4; ++nt) {
            const int n  = c * 64 + nt * 16 + lr;
            const int kb = kt * 32 + lg * 8;
            s16x8 f;
            #pragma unroll
            for (int i = 0; i < 8; ++i) f[i] = f2bf(W1[(size_t)(kb + i) * HF + n]);
            bfrag[kt][nt] = f;
        }
    float b1v[4], w2v[4];
    #pragma unroll
    for (int nt = 0; nt < 4; ++nt) {
        const int n = c * 64 + nt * 16 + lr;
        b1v[nt] = b1[n];
        w2v[nt] = W2[n];
    }
    const float b2v = b2[0];

    const int g = gridDim.x;
    const int tile0 = blockIdx.x;

    // ---- prologue: ids + gather for tile0; ids for tile0+g ----
    s16x8 Aa[8], Ab[8];
    {
        int e = tile0 * MTILE + myrow;
        e = e < N_EDGES ? e : N_EDGES - 1;
        int sidC = src[e], didC = dst[e];
        gatherA(hb, sidC, didC, lg, Aa);
    }
    int sidA, didA;
    {
        int e = (tile0 + g) * MTILE + myrow;
        e = e < N_EDGES ? e : N_EDGES - 1;
        sidA = src[e]; didA = dst[e];
    }
    int sidB, didB;

    int pp = 0;
    for (int tile = tile0; tile < NTILES; tile += 2 * g) {
        step_tile(tile, g, hb, src, dst, Aa, Ab, sidA, didA, sidB, didB,
                  bfrag, b1v, w2v, b2v, out, lds_p, pp, t, r, c, lg, lr, myrow);
        pp ^= 1;
        if (tile + g < NTILES) {
            step_tile(tile + g, g, hb, src, dst, Ab, Aa, sidB, didB, sidA, didA,
                      bfrag, b1v, w2v, b2v, out, lds_p, pp, t, r, c, lg, lr, myrow);
            pp ^= 1;
        }
    }
}

// ---------------------------------------------------------------------------
// Round-0 fallback (LDS-staged, fp32 gather) — used only if ws too small.
// ---------------------------------------------------------------------------
__global__ __launch_bounds__(256, 3) void mlp_edge_score(
    const float* __restrict__ h,
    const int*   __restrict__ src,
    const int*   __restrict__ dst,
    const float* __restrict__ W1,
    const float* __restrict__ b1,
    const float* __restrict__ W2,
    const float* __restrict__ b2,
    float* __restrict__ out)
{
    __shared__ short lds_a[MTILE * K2];
    __shared__ float lds_p[4][MTILE];

    const int t  = threadIdx.x;
    const int w  = t >> 6;
    const int l  = t & 63;
    const int lg = l >> 4;
    const int lr = l & 15;

    s16x8 bfrag[8][2];
    #pragma unroll
    for (int kt = 0; kt < 8; ++kt) {
      #pragma unroll
      for (int nt = 0; nt < 2; ++nt) {
        const int n  = w * 32 + nt * 16 + lr;
        const int kb = kt * 32 + lg * 8;
        s16x8 f;
        #pragma unroll
        for (int i = 0; i < 8; ++i) f[i] = f2bf(W1[(kb + i) * HF + n]);
        bfrag[kt][nt] = f;
      }
    }
    float b1v[2], w2v[2];
    #pragma unroll
    for (int nt = 0; nt < 2; ++nt) {
      const int n = w * 32 + nt * 16 + lr;
      b1v[nt] = b1[n];
      w2v[nt] = W2[n];
    }
    const float b2v = b2[0];
    char* const abase = (char*)lds_a;

    for (int tile = blockIdx.x; tile < NTILES; tile += gridDim.x) {
      const int base = tile * MTILE;
      {
        const int r = l;
        int e = base + r; if (e >= N_EDGES) e = N_EDGES - 1;
        const int node = (w & 2) ? dst[e] : src[e];
        const float* hp = h + (size_t)node * HF + (w & 1) * 64;
        const int bohi = (w >> 1) * 256 + (w & 1) * 128;
        const int sw   = (r & 7) << 4;
        char* rowp = abase + r * 512 + bohi;
        #pragma unroll
        for (int j = 0; j < 8; ++j) {
          f32x4 v0 = *reinterpret_cast<const f32x4*>(hp + j * 8);
          f32x4 v1 = *reinterpret_cast<const f32x4*>(hp + j * 8 + 4);
          s16x8 p;
          p[0]=f2bf(v0[0]); p[1]=f2bf(v0[1]); p[2]=f2bf(v0[2]); p[3]=f2bf(v0[3]);
          p[4]=f2bf(v1[0]); p[5]=f2bf(v1[1]); p[6]=f2bf(v1[2]); p[7]=f2bf(v1[3]);
          *reinterpret_cast<s16x8*>(rowp + ((j * 16) ^ sw)) = p;
        }
      }
      __syncthreads();

      f32x4 acc[4][2];
      #pragma unroll
      for (int mt = 0; mt < 4; ++mt) {
        acc[mt][0] = (f32x4){0.f, 0.f, 0.f, 0.f};
        acc[mt][1] = (f32x4){0.f, 0.f, 0.f, 0.f};
      }
      #pragma unroll
      for (int kt = 0; kt < 8; ++kt) {
        s16x8 afr[4];
        #pragma unroll
        for (int mt = 0; mt < 4; ++mt) {
          const int row = mt * 16 + lr;
          const int bo  = (kt * 64 + lg * 16) ^ ((row & 7) << 4);
          afr[mt] = *reinterpret_cast<const s16x8*>(abase + row * 512 + bo);
        }
        #pragma unroll
        for (int mt = 0; mt < 4; ++mt) {
          acc[mt][0] = __builtin_amdgcn_mfma_f32_16x16x32_bf16(afr[mt], bfrag[kt][0], acc[mt][0], 0, 0, 0);
          acc[mt][1] = __builtin_amdgcn_mfma_f32_16x16x32_bf16(afr[mt], bfrag[kt][1], acc[mt][1], 0, 0, 0);
        }
      }

      float s[4][4];
      #pragma unroll
      for (int mt = 0; mt < 4; ++mt)
        #pragma unroll
        for (int rr = 0; rr < 4; ++rr) {
          float v0 = acc[mt][0][rr] + b1v[0]; v0 = v0 > 0.f ? v0 : 0.f;
          float v1 = acc[mt][1][rr] + b1v[1]; v1 = v1 > 0.f ? v1 : 0.f;
          s[mt][rr] = v0 * w2v[0] + v1 * w2v[1];
        }
      #pragma unroll
      for (int mask = 1; mask <= 8; mask <<= 1)
        #pragma unroll
        for (int mt = 0; mt < 4; ++mt)
          #pragma unroll
          for (int rr = 0; rr < 4; ++rr)
            s[mt][rr] += __shfl_xor(s[mt][rr], mask, 64);

      if (lr == 0) {
        #pragma unroll
        for (int mt = 0; mt < 4; ++mt)
          #pragma unroll
          for (int rr = 0; rr < 4; ++rr)
            lds_p[w][mt * 16 + lg * 4 + rr] = s[mt][rr];
      }
      __syncthreads();

      if (t < MTILE) {
        const int e = base + t;
        if (e < N_EDGES)
          out[e] = lds_p[0][t] + lds_p[1][t] + lds_p[2][t] + lds_p[3][t] + b2v;
      }
    }
}

extern "C" void kernel_launch(void* const* d_in, const int* in_sizes, int n_in,
                              void* d_out, int out_size, void* d_ws, size_t ws_size,
                              hipStream_t stream) {
    const float* h   = (const float*)d_in[0];
    const int*   src = (const int*)  d_in[1];
    const int*   dst = (const int*)  d_in[2];
    const float* W1  = (const float*)d_in[3];
    const float* b1  = (const float*)d_in[4];
    const float* W2  = (const float*)d_in[5];
    const float* b2  = (const float*)d_in[6];
    float* out = (float*)d_out;

    if (ws_size >= HB_BYTES) {
        short* hb = (short*)d_ws;
        const int n8 = N_NODES * HF / 8;
        conv_h_kernel<<<(n8 + 255) / 256, 256, 0, stream>>>(h, hb);
        mlp_edge_score_v2<<<MAIN_BLOCKS, 512, 0, stream>>>(hb, src, dst, W1, b1, W2, b2, out);
    } else {
        mlp_edge_score<<<2048, 256, 0, stream>>>(h, src, dst, W1, b1, W2, b2, out);
    }
}